// Round 2
// baseline (197.704 us; speedup 1.0000x reference)
//
#include <hip/hip_runtime.h>
#include <cstdint>

// Problem constants (fixed by setup_inputs): B=4, N=16384, P=1024, C=128
#define BQ_B 4
#define BQ_N 16384
#define BQ_P 1024
#define BQ_C 128
#define NS   64
#define R2   0.04f

// Output layout (flat concat, fp32):
//   region 1: new_features (B,131,P,NS)
//   region 2: grouped_xyz  (B,3,P,NS)
//   region 3: idx0         (B,P,NS) stored as float
#define O1 ((size_t)BQ_B * 131 * BQ_P * NS)
#define O2 (O1 + (size_t)BQ_B * 3 * BQ_P * NS)

typedef float v4f __attribute__((ext_vector_type(4)));
typedef int   v4i __attribute__((ext_vector_type(4)));

// ws layout: wsIdx (B*P, NS) int32 at offset 0 (1 MB).

// ---------------- Kernel 1: ball query, one WAVE per center ----------------
// 4096 centers = 4096 waves (1024 blocks x 4 waves). No __syncthreads.
// Software-pipelined: chunk i+1's 512-point loads are issued BEFORE the
// ballot/rank chain of chunk i, so L2 latency hides under the scalar chain.
__global__ __launch_bounds__(256) void ballquery_kernel(
    const float* __restrict__ xyz,      // (B, N, 3)
    const float* __restrict__ new_xyz,  // (B, P, 3)
    int* __restrict__ wsIdx,            // (B*P, NS) gather index (BQ_N = pad)
    float* __restrict__ out)
{
#pragma clang fp contract(off)   // match np reference exactly at the radius boundary
    const int lane = threadIdx.x & 63;
    const int w    = threadIdx.x >> 6;            // wave 0..3
    const int center = blockIdx.x * 4 + w;
    const int b = center >> 10;
    const int p = center & (BQ_P - 1);

    __shared__ int lidx[4][NS];                   // per-wave strip

    const float cx = new_xyz[center * 3 + 0];
    const float cy = new_xyz[center * 3 + 1];
    const float cz = new_xyz[center * 3 + 2];
    const float* xb = xyz + (size_t)b * BQ_N * 3;

    const unsigned long long lmask = (1ull << lane) - 1ull;
    int total = 0;

    // preload chunk 0 (8 x 64 points, 12 B/lane each)
    float px[8], py[8], pz[8];
    #pragma unroll
    for (int u = 0; u < 8; ++u) {
        const int i = u * 64 + lane;
        px[u] = xb[i * 3 + 0];
        py[u] = xb[i * 3 + 1];
        pz[u] = xb[i * 3 + 2];
    }

    int base = 0;
    for (;;) {
        const int nbase = base + 512;
        // fire next chunk's loads before touching current chunk's values
        float nx[8], ny[8], nz[8];
        if (nbase < BQ_N) {
            #pragma unroll
            for (int u = 0; u < 8; ++u) {
                const int i = nbase + u * 64 + lane;
                nx[u] = xb[i * 3 + 0];
                ny[u] = xb[i * 3 + 1];
                nz[u] = xb[i * 3 + 2];
            }
        }
        // process current chunk: 8 independent ballots, then rank assignment
        unsigned long long m[8];
        #pragma unroll
        for (int u = 0; u < 8; ++u) {
            const float dx = px[u] - cx;
            const float dy = py[u] - cy;
            const float dz = pz[u] - cz;
            m[u] = __ballot(dx * dx + dy * dy + dz * dz < R2);
        }
        #pragma unroll
        for (int u = 0; u < 8; ++u) {
            if ((m[u] >> lane) & 1ull) {
                const int r = total + (int)__popcll(m[u] & lmask);
                if (r < NS) lidx[w][r] = base + u * 64 + lane;
            }
            total += (int)__popcll(m[u]);         // wave-uniform (scalar)
        }
        if (total >= NS || nbase >= BQ_N) break;  // uniform branch
        base = nbase;
        #pragma unroll
        for (int u = 0; u < 8; ++u) { px[u] = nx[u]; py[u] = ny[u]; pz[u] = nz[u]; }
    }
    __threadfence_block();   // drain lgkm: same-wave LDS RAW before the reads below

    const int tt    = (total > NS) ? NS : total;
    const int first = (total > 0) ? lidx[w][0] : BQ_N;
    const int v     = (lane < tt) ? lidx[w][lane] : BQ_N;   // BQ_N = pad slot
    const int idx0  = (lane < tt) ? v : first;
    const bool real = v < BQ_N;

    wsIdx[(size_t)center * NS + lane] = v;        // cached: re-read by gather
    __builtin_nontemporal_store((float)idx0, &out[O2 + (size_t)center * NS + lane]);

    #pragma unroll
    for (int d = 0; d < 3; ++d) {
        const float c  = (d == 0) ? cx : ((d == 1) ? cy : cz);
        const float pt = real ? xb[v * 3 + d] : 1000000.0f;
        const float g  = pt - c;
        __builtin_nontemporal_store(g,
            &out[O1 + ((size_t)(b * 3 + d) * BQ_P + p) * NS + lane]);
        const float xf = ((g > 100000.0f) ? 0.0f : g) / 0.2f;
        __builtin_nontemporal_store(xf,
            &out[((size_t)(b * 131 + d) * BQ_P + p) * NS + lane]);
    }
}

// ---------------- Kernel 2: per-(b,c) channel-row gather ----------------
// One block per (batch, channel): stage features[b][c][0:N] (64 KB) in LDS,
// then emit the (P,NS) output plane for that channel. Index quads are
// prefetched 4 iterations ahead (first 4 fired before the staging barrier);
// output goes out via nontemporal float4 stores (write-once stream),
// features come in via nontemporal loads (read-once stream) — L2 stays
// reserved for the hot wsIdx slices.
__global__ __launch_bounds__(512) void feat_gather_kernel(
    const float* __restrict__ features, // (B, C, N)
    const int* __restrict__ wsIdx,      // (B*P, NS)
    float* __restrict__ out)
{
    const int b = blockIdx.x >> 7;
    const int c = blockIdx.x & 127;
    const int t = threadIdx.x;

    __shared__ float row[BQ_N];         // 65536 B: 2 blocks/CU

    const v4i* gi4 = (const v4i*)(wsIdx + (size_t)b * BQ_P * NS);  // L2-hot
    // fire first 4 index quads before the row-staging barrier
    v4i g[4];
    #pragma unroll
    for (int j = 0; j < 4; ++j) g[j] = gi4[j * 512 + t];

    const v4f* fr = (const v4f*)(features + ((size_t)b * BQ_C + c) * BQ_N);
    v4f* row4 = (v4f*)row;
    #pragma unroll
    for (int k = 0; k < 8; ++k)         // 512 thr x 8 x 16 B = 64 KB coalesced
        row4[k * 512 + t] = __builtin_nontemporal_load(&fr[k * 512 + t]);
    __syncthreads();

    v4f* op = (v4f*)(out + (size_t)(b * 131 + 3 + c) * BQ_P * NS);
    for (int kk = 0; kk < 32; kk += 4) {
        v4i n[4];
        const bool more = (kk + 4) < 32;
        if (more) {
            #pragma unroll
            for (int j = 0; j < 4; ++j) n[j] = gi4[(kk + 4 + j) * 512 + t];
        }
        #pragma unroll
        for (int j = 0; j < 4; ++j) {
            const v4i gi = g[j];
            v4f v;
            v.x = (gi.x < BQ_N) ? row[gi.x] : 0.0f;   // pad slot -> 0 (feats_pad)
            v.y = (gi.y < BQ_N) ? row[gi.y] : 0.0f;
            v.z = (gi.z < BQ_N) ? row[gi.z] : 0.0f;
            v.w = (gi.w < BQ_N) ? row[gi.w] : 0.0f;
            __builtin_nontemporal_store(v, &op[(kk + j) * 512 + t]);
        }
        if (more) {
            #pragma unroll
            for (int j = 0; j < 4; ++j) g[j] = n[j];
        }
    }
}

extern "C" void kernel_launch(void* const* d_in, const int* in_sizes, int n_in,
                              void* d_out, int out_size, void* d_ws, size_t ws_size,
                              hipStream_t stream) {
    const float* xyz      = (const float*)d_in[0];  // (4,16384,3)
    const float* new_xyz  = (const float*)d_in[1];  // (4,1024,3)
    const float* features = (const float*)d_in[2];  // (4,128,16384)
    float* out = (float*)d_out;
    int*   wsIdx = (int*)d_ws;

    ballquery_kernel<<<dim3(BQ_B * BQ_P / 4), dim3(256), 0, stream>>>(xyz, new_xyz, wsIdx, out);
    feat_gather_kernel<<<dim3(BQ_B * BQ_C), dim3(512), 0, stream>>>(features, wsIdx, out);
}